// Round 9
// baseline (1369.245 us; speedup 1.0000x reference)
//
#include <hip/hip_runtime.h>

#define HH    51
#define T_SEQ 1024
#define T_TOT 1088
#define B_TOT 4096
#define MT    16
#define NTH   512

typedef __attribute__((ext_vector_type(8))) short bf8_t;   // 8 bf16 (4 VGPRs)
typedef __attribute__((ext_vector_type(4))) float f32x4;   // MFMA C/D

// ---- LDS layout (bytes) ----
#define H1H_O 0       // [2][16][128] bf16 hi, XOR-swizzled rows
#define H1L_O 4096
#define H2H_O 8192
#define H2L_O 12288
#define XB_O  16384   // float [2][16][16]
#define OB_O  18432   // float [2][16][16]
#define PT_O  20480   // float [2][4][16]
#define SM_SZ 20992

#define L2E 1.44269504088896f

#if __has_builtin(__builtin_amdgcn_exp2f)
#define FEXP2 __builtin_amdgcn_exp2f
#else
#define FEXP2 exp2f
#endif
#if __has_builtin(__builtin_amdgcn_rcpf)
#define FRCP __builtin_amdgcn_rcpf
#else
#define FRCP(v) (1.f / (v))
#endif

__device__ __forceinline__ short f2bf(float f) {            // RNE (setup only)
  unsigned u = __builtin_bit_cast(unsigned, f);
  u += 0x7fffu + ((u >> 16) & 1u);
  return (short)(u >> 16);
}
__device__ __forceinline__ float bf2f(short s) {
  unsigned u = ((unsigned)(unsigned short)s) << 16;
  return __builtin_bit_cast(float, u);
}
// lsig(v) = 1/(1+2^v).  sigma(x)=lsig(-L2E*x) ; tanh(x)=1-2*lsig(2*L2E*x)
__device__ __forceinline__ float lsig(float v) { return FRCP(1.f + FEXP2(v)); }

__device__ __forceinline__ f32x4 MFMA(bf8_t a, bf8_t b, f32x4 c) {
  return __builtin_amdgcn_mfma_f32_16x16x32_bf16(a, b, c, 0, 0, 0);
}
__device__ __forceinline__ bf8_t ldA(const char* base, int row, int off) {
  off ^= ((row & 7) << 4);
  return *reinterpret_cast<const bf8_t*>(base + row * 128 + off);
}
// truncation hi/lo split store: exact residual, err <= 2^-16 rel
__device__ __forceinline__ void sthl(char* WH, char* WL, int row, int boff, float v) {
  const int o = row * 128 + (boff ^ ((row & 7) << 4));
  const unsigned u = __builtin_bit_cast(unsigned, v);
  *reinterpret_cast<short*>(WH + o) = (short)(u >> 16);
  const float rem = v - __builtin_bit_cast(float, u & 0xffff0000u);
  *reinterpret_cast<short*>(WL + o) = (short)(__builtin_bit_cast(unsigned, rem) >> 16);
}

__global__ __launch_bounds__(NTH, 1)
void lstm_mfma_kernel(const float* __restrict__ x,
                      const float* __restrict__ Wih1, const float* __restrict__ Whh1,
                      const float* __restrict__ bih1, const float* __restrict__ bhh1,
                      const float* __restrict__ Wih2, const float* __restrict__ Whh2,
                      const float* __restrict__ bih2, const float* __restrict__ bhh2,
                      const float* __restrict__ Wlin, const float* __restrict__ blin,
                      float* __restrict__ out)
{
  extern __shared__ char smc[];
  float* smf = (float*)smc;
  const int tid  = threadIdx.x;
  const int lane = tid & 63;
  const int w    = tid >> 6;
  const int cl   = lane & 15;
  const int gr   = lane >> 4;
  const int rng  = w & 3;
  const bool isL2 = (w >= 4);
  const int jo   = rng * 16 + cl;
  const bool jv  = (jo < HH);
  const int bg0  = blockIdx.x * MT;

  for (int i = tid; i < SM_SZ / 4; i += NTH) smf[i] = 0.f;

  // gate-domain scales folded into weights/biases: i,f,o -> -L2E ; g -> +2*L2E
  const float gsc[4] = {-L2E, -L2E, 2.f * L2E, -L2E};

  // ---- B-fragments (weights, bf16 hi/lo, pre-scaled) in registers ----
  // k̂ = kb*32 + gr*8 + s.  L1: kb0-1 = Whh1, plus k=53 carries Wih1 (x slot).
  // L2: kb0-1 = Wih2, kb2-3 = Whh2.
  bf8_t Bh[4][4], Bl[4][4];
  #pragma unroll
  for (int g = 0; g < 4; ++g) {
    #pragma unroll
    for (int kb = 0; kb < 4; ++kb) {
      bf8_t vh, vl;
      const bool dead = (!isL2 && kb >= 2);
      const float* Wsrc = isL2 ? (kb < 2 ? Wih2 : Whh2) : Whh1;
      const int kbase = (kb & 1) * 32;
      #pragma unroll
      for (int s = 0; s < 8; ++s) {
        const int ku = kbase + gr * 8 + s;
        float v = (!dead && jv && ku < HH) ? Wsrc[(g * HH + jo) * HH + ku] * gsc[g] : 0.f;
        if (!isL2 && kb == 1 && ku == 53) v = jv ? Wih1[g * HH + jo] * gsc[g] : 0.f;
        const short hh = f2bf(v);
        vh[s] = hh;
        vl[s] = f2bf(v - bf2f(hh));
      }
      Bh[g][kb] = vh; Bl[g][kb] = vl;
    }
  }
  // Wlin B-fragments: col 0 = Wlin hi, col 1 = Wlin lo.
  bf8_t Bo[2];
  #pragma unroll
  for (int kb = 0; kb < 2; ++kb) {
    bf8_t v;
    #pragma unroll
    for (int s = 0; s < 8; ++s) {
      const int ku = kb * 32 + gr * 8 + s;
      float wv = (ku < HH) ? Wlin[ku] : 0.f;
      const short hh = f2bf(wv);
      v[s] = (cl == 0) ? hh : (cl == 1) ? f2bf(wv - bf2f(hh)) : (short)0;
    }
    Bo[kb] = v;
  }
  float cbv[4], wih1v[4];
  #pragma unroll
  for (int g = 0; g < 4; ++g) {
    cbv[g]   = jv ? (isL2 ? (bih2[g*HH+jo] + bhh2[g*HH+jo])
                          : (bih1[g*HH+jo] + bhh1[g*HH+jo])) * gsc[g] : 0.f;
    wih1v[g] = (jv && !isL2) ? Wih1[g*HH+jo] * gsc[g] : 0.f;
  }
  const float wlv = (jv && isL2) ? Wlin[jo] : 0.f;
  const float bl  = blin[0];
  float cst[4] = {0.f, 0.f, 0.f, 0.f};

  auto act_h = [&](const f32x4 acc[4], int r) -> float {
    const float si = lsig(acc[0][r]);
    const float sf = lsig(acc[1][r]);
    const float tg = 1.f - 2.f * lsig(acc[2][r]);
    const float so = lsig(acc[3][r]);
    const float cn = sf * cst[r] + si * tg;
    cst[r] = cn;
    return so * (1.f - 2.f * lsig(cn * (2.f * L2E)));
  };

  auto writeOB = [&](int tw, const float ov[4]) {
    if (cl == 0) {
      const int po = (tw >> 4) & 1, cc = tw & 15;
      #pragma unroll
      for (int r = 0; r < 4; ++r)
        smf[OB_O/4 + po*256 + (gr*4 + r)*16 + cc] = ov[r];
    }
  };

  // ---- L2 h1-fragment preload registers (survive across the barrier) ----
  bf8_t pa0, pa1, pl0, pl1;
  auto l2_preload = [&](const int hb) {
    const char* RH = smc + H1H_O + hb * 2048;
    const char* RL = smc + H1L_O + hb * 2048;
    pa0 = ldA(RH, cl, gr*16); pa1 = ldA(RH, cl, 64 + gr*16);
    pl0 = ldA(RL, cl, gr*16); pl1 = ldA(RL, cl, 64 + gr*16);
  };

  // xv == nullptr -> main phase (x enters via k=53 of the A fragments)
  auto do_l1 = [&](const int rb, const int wb, const float* xv,
                   const bool seedx, const int t) {
    const char* RH = smc + H1H_O + rb * 2048;
    const char* RL = smc + H1L_O + rb * 2048;
    bf8_t a0 = ldA(RH, cl, gr*16), a1 = ldA(RH, cl, 64 + gr*16);
    bf8_t l0 = ldA(RL, cl, gr*16), l1 = ldA(RL, cl, 64 + gr*16);
    f32x4 acc[4];
    __builtin_amdgcn_s_setprio(1);
    #pragma unroll
    for (int g = 0; g < 4; ++g) {
      f32x4 aa = {cbv[g], cbv[g], cbv[g], cbv[g]};
      aa = MFMA(a0, Bh[g][0], aa); aa = MFMA(a1, Bh[g][1], aa); aa = MFMA(l0, Bh[g][0], aa);
      f32x4 ab = {0.f, 0.f, 0.f, 0.f};
      ab = MFMA(l1, Bh[g][1], ab); ab = MFMA(a0, Bl[g][0], ab); ab = MFMA(a1, Bl[g][1], ab);
      #pragma unroll
      for (int r2 = 0; r2 < 4; ++r2) acc[g][r2] = aa[r2] + ab[r2];
    }
    __builtin_amdgcn_s_setprio(0);
    if (xv) {
      #pragma unroll
      for (int g = 0; g < 4; ++g)
        #pragma unroll
        for (int r = 0; r < 4; ++r) acc[g][r] += wih1v[g] * xv[r];
    }
    char* WH = smc + H1H_O + wb * 2048;
    char* WL = smc + H1L_O + wb * 2048;
    #pragma unroll
    for (int r = 0; r < 4; ++r) {
      const float hv = act_h(acc, r);
      if (jv) sthl(WH, WL, gr * 4 + r, 2 * jo, hv);
    }
    if (seedx && rng == 3 && lane < 16) {
      const float xn = smf[XB_O/4 + (((t+1) >> 4) & 1) * 256 + lane * 16 + ((t+1) & 15)];
      sthl(WH, WL, lane, 2 * 53, xn);
    }
  };

  // h1b >= 0: load h1 frags fresh (AR); else use preloaded registers.
  auto do_l2 = [&](const int h1b, const int h2r, const int h2w,
                   const bool wantPT, const int ptq, const int tw) {
    bf8_t a0, a1, u0, u1;
    if (h1b >= 0) {
      const char* R1H = smc + H1H_O + h1b * 2048;
      const char* R1L = smc + H1L_O + h1b * 2048;
      a0 = ldA(R1H, cl, gr*16); a1 = ldA(R1H, cl, 64 + gr*16);
      u0 = ldA(R1L, cl, gr*16); u1 = ldA(R1L, cl, 64 + gr*16);
    } else { a0 = pa0; a1 = pa1; u0 = pl0; u1 = pl1; }
    const char* R2H = smc + H2H_O + h2r * 2048;
    const char* R2L = smc + H2L_O + h2r * 2048;
    bf8_t b0 = ldA(R2H, cl, gr*16), b1 = ldA(R2H, cl, 64 + gr*16);
    bf8_t v0 = ldA(R2L, cl, gr*16), v1 = ldA(R2L, cl, 64 + gr*16);
    f32x4 acc[4];
    f32x4 d = {0.f, 0.f, 0.f, 0.f};
    __builtin_amdgcn_s_setprio(1);
    #pragma unroll
    for (int g = 0; g < 4; ++g) {
      f32x4 aa = {cbv[g], cbv[g], cbv[g], cbv[g]};           // h1-side (preloaded)
      aa = MFMA(a0, Bh[g][0], aa); aa = MFMA(a1, Bh[g][1], aa);
      aa = MFMA(u0, Bh[g][0], aa); aa = MFMA(u1, Bh[g][1], aa);
      aa = MFMA(a0, Bl[g][0], aa); aa = MFMA(a1, Bl[g][1], aa);
      f32x4 ab = {0.f, 0.f, 0.f, 0.f};                       // h2-side
      ab = MFMA(b0, Bh[g][2], ab); ab = MFMA(b1, Bh[g][3], ab);
      ab = MFMA(v0, Bh[g][2], ab); ab = MFMA(v1, Bh[g][3], ab);
      ab = MFMA(b0, Bl[g][2], ab); ab = MFMA(b1, Bl[g][3], ab);
      #pragma unroll
      for (int r2 = 0; r2 < 4; ++r2) acc[g][r2] = aa[r2] + ab[r2];
    }
    if (tw >= 0 && rng == 0) {    // out(tw) = h2(tw)·Wlin via 4 MFMAs (wave 4)
      d = MFMA(b1, Bo[1], d); d = MFMA(b0, Bo[0], d);
      d = MFMA(v1, Bo[1], d); d = MFMA(v0, Bo[0], d);
    }
    __builtin_amdgcn_s_setprio(0);
    char* WH = smc + H2H_O + h2w * 2048;
    char* WL = smc + H2L_O + h2w * 2048;
    float po[4];
    #pragma unroll
    for (int r = 0; r < 4; ++r) {
      const float hv = act_h(acc, r);
      if (jv) sthl(WH, WL, gr * 4 + r, 2 * jo, hv);
      po[r] = wlv * hv;
    }
    if (tw >= 0 && rng == 0) {
      float ov[4];
      #pragma unroll
      for (int r = 0; r < 4; ++r) ov[r] = d[r] + __shfl_xor(d[r], 1, 64) + bl;
      writeOB(tw, ov);
    }
    if (wantPT) {
      #pragma unroll
      for (int r = 0; r < 4; ++r) {
        #pragma unroll
        for (int m = 1; m < 16; m <<= 1) po[r] += __shfl_xor(po[r], m, 64);
      }
      if (cl == 0) {
        #pragma unroll
        for (int r = 0; r < 4; ++r)
          smf[PT_O/4 + ptq*64 + rng*16 + gr*4 + r] = po[r];
      }
    }
  };

  auto finalize = [&](const int q, float ov[4]) {
    #pragma unroll
    for (int r = 0; r < 4; ++r) {
      const int row = gr * 4 + r;
      ov[r] = smf[PT_O/4 + q*64 +  0 + row] + smf[PT_O/4 + q*64 + 16 + row]
            + smf[PT_O/4 + q*64 + 32 + row] + smf[PT_O/4 + q*64 + 48 + row] + bl;
    }
  };
  auto flushOB = [&](int tb) {
    const int q = (tb >> 4) & 1;
    #pragma unroll
    for (int it = 0; it < 4; ++it) {
      const int idx = lane + 64 * it;
      const int r = idx >> 4, tt = idx & 15;
      out[(size_t)(bg0 + r) * T_TOT + tb + tt] = smf[OB_O/4 + q*256 + r*16 + tt];
    }
  };

  __syncthreads();
  if (tid < 256) {
    const int r = tid >> 4, tt = tid & 15;
    smf[XB_O/4 + r*16 + tt] = x[(size_t)(bg0 + r) * T_SEQ + tt];
  }
  if (tid < 16)   // seed x(0) into k=53 of h1 buf 1 (read buffer of l1(0))
    sthl(smc + H1H_O + 2048, smc + H1L_O + 2048, tid, 2 * 53,
         x[(size_t)(bg0 + tid) * T_SEQ]);
  __syncthreads();

  // ======== main pipeline: layer1(t) || layer2(t-2); 1 barrier/step ========
  #pragma unroll 1
  for (int t2 = 0; t2 < T_SEQ; t2 += 2) {
    {  // even substep, p = 0
      const int t = t2;
      if (!isL2) {
        if ((w == 1 || w == 2) && (t & 15) == 0 && (t + 16) < T_SEQ) {
          const int nt = t + 16, par = (nt >> 4) & 1;
          #pragma unroll
          for (int it = 0; it < 2; ++it) {
            const int idx = (w - 1) * 128 + lane + 64 * it;
            const int r = idx >> 4, tt = idx & 15;
            smf[XB_O/4 + par*256 + r*16 + tt] = x[(size_t)(bg0 + r) * T_SEQ + nt + tt];
          }
        }
        do_l1(1, 0, nullptr, true, t);
      } else {
        if (t >= 2) do_l2(-1, 1, 0, false, 0, t - 3);
        if (t >= 1) l2_preload(1);
      }
      __syncthreads();
    }
    {  // odd substep, p = 1
      const int t = t2 + 1;
      if (!isL2) {
        if (w == 3 && (t & 15) == 9 && t >= 25) flushOB(((t - 2) & ~15) - 16);
        do_l1(0, 1, nullptr, (t + 1) < T_SEQ, t);
      } else {
        if (t >= 2) do_l2(-1, 0, 1, false, 0, t - 3);
        l2_preload(0);
      }
      __syncthreads();
    }
  }

  // ---- drain A: layer2(1022); zero stale k53 x-slots for AR ----
  if (isL2) {
    do_l2(-1, 1, 0, false, 0, 1021);
    l2_preload(1);                       // h1(1023) for tau=1023
  } else if (w == 3 && lane < 16) {
    sthl(smc + H1H_O,        smc + H1L_O,        lane, 2 * 53, 0.f);
    sthl(smc + H1H_O + 2048, smc + H1L_O + 2048, lane, 2 * 53, 0.f);
  }
  __syncthreads();
  // ---- drain B: layer2(1023) -> PT[1] (out 1023) + proj out(1022) ----
  if (isL2) do_l2(-1, 0, 1, true, 1, 1022);
  __syncthreads();

  // ======== autoregressive region: 2 serial phases/step (PT path) ========
  auto ar_step = [&](int t, const int p) {
    if (!isL2) {
      float ov[4];
      finalize(p ^ 1, ov);
      if (w == 0) writeOB(t - 1, ov);
      if (w == 3 && (t & 15) == 8) flushOB(((t - 1) & ~15) - 16);
      do_l1(p ^ 1, p, ov, false, t);
    }
    __syncthreads();
    if (isL2) do_l2(p, p ^ 1, p, true, p, -1);
    __syncthreads();
  };
  #pragma unroll 1
  for (int t = T_SEQ; t < T_TOT; t += 2) {
    ar_step(t, 0);
    ar_step(t + 1, 1);
  }
  if (!isL2 && w == 0) { float ov[4]; finalize(1, ov); writeOB(T_TOT - 1, ov); }
  __syncthreads();
  if (w == 3) flushOB(T_TOT - 16);
}

extern "C" void kernel_launch(void* const* d_in, const int* in_sizes, int n_in,
                              void* d_out, int out_size, void* d_ws, size_t ws_size,
                              hipStream_t stream) {
  const float* x    = (const float*)d_in[0];
  const float* Wih1 = (const float*)d_in[1];
  const float* Whh1 = (const float*)d_in[2];
  const float* bih1 = (const float*)d_in[3];
  const float* bhh1 = (const float*)d_in[4];
  const float* Wih2 = (const float*)d_in[5];
  const float* Whh2 = (const float*)d_in[6];
  const float* bih2 = (const float*)d_in[7];
  const float* bhh2 = (const float*)d_in[8];
  const float* Wlin = (const float*)d_in[9];
  const float* blin = (const float*)d_in[10];
  float* out = (float*)d_out;

  lstm_mfma_kernel<<<B_TOT / MT, NTH, SM_SZ, stream>>>(
      x, Wih1, Whh1, bih1, bhh1, Wih2, Whh2, bih2, bhh2, Wlin, blin, out);
}

// Round 10
// 1300.250 us; speedup vs baseline: 1.0531x; 1.0531x over previous
//
#include <hip/hip_runtime.h>

#define HH    51
#define T_SEQ 1024
#define T_TOT 1088
#define B_TOT 4096
#define MT    16
#define NTH   512

typedef __attribute__((ext_vector_type(8))) short bf8_t;   // 8 bf16 (4 VGPRs)
typedef __attribute__((ext_vector_type(4))) float f32x4;   // MFMA C/D

// ---- LDS layout (bytes) ----
#define H1H_O 0
#define H1L_O 4096
#define H2H_O 8192
#define H2L_O 12288
#define XB_O  16384   // float [2][16][16]
#define OB_O  18432   // float [2][16][16]
#define PT_O  20480   // float [2][4][16]
#define SM_SZ 20992

#define L2E 1.44269504088896f

#if __has_builtin(__builtin_amdgcn_exp2f)
#define FEXP2 __builtin_amdgcn_exp2f
#else
#define FEXP2 exp2f
#endif
#if __has_builtin(__builtin_amdgcn_rcpf)
#define FRCP __builtin_amdgcn_rcpf
#else
#define FRCP(v) (1.f / (v))
#endif

__device__ __forceinline__ short f2bf(float f) {            // RNE (setup only)
  unsigned u = __builtin_bit_cast(unsigned, f);
  u += 0x7fffu + ((u >> 16) & 1u);
  return (short)(u >> 16);
}
__device__ __forceinline__ float bf2f(short s) {
  unsigned u = ((unsigned)(unsigned short)s) << 16;
  return __builtin_bit_cast(float, u);
}

__device__ __forceinline__ f32x4 MFMA(bf8_t a, bf8_t b, f32x4 c) {
  return __builtin_amdgcn_mfma_f32_16x16x32_bf16(a, b, c, 0, 0, 0);
}
__device__ __forceinline__ bf8_t ldA(const char* base, int row, int off) {
  off ^= ((row & 7) << 4);
  return *reinterpret_cast<const bf8_t*>(base + row * 128 + off);
}
// truncation hi/lo split store: exact residual, err <= 2^-16 rel
__device__ __forceinline__ void sthl(char* WH, char* WL, int row, int boff, float v) {
  const int o = row * 128 + (boff ^ ((row & 7) << 4));
  const unsigned u = __builtin_bit_cast(unsigned, v);
  *reinterpret_cast<short*>(WH + o) = (short)(u >> 16);
  const float rem = v - __builtin_bit_cast(float, u & 0xffff0000u);
  *reinterpret_cast<short*>(WL + o) = (short)(__builtin_bit_cast(unsigned, rem) >> 16);
}

__global__ __launch_bounds__(NTH, 1)
void lstm_mfma_kernel(const float* __restrict__ x,
                      const float* __restrict__ Wih1, const float* __restrict__ Whh1,
                      const float* __restrict__ bih1, const float* __restrict__ bhh1,
                      const float* __restrict__ Wih2, const float* __restrict__ Whh2,
                      const float* __restrict__ bih2, const float* __restrict__ bhh2,
                      const float* __restrict__ Wlin, const float* __restrict__ blin,
                      float* __restrict__ out)
{
  extern __shared__ char smc[];
  float* smf = (float*)smc;
  const int tid  = threadIdx.x;
  const int lane = tid & 63;
  const int w    = tid >> 6;
  const int cl   = lane & 15;
  const int gr   = lane >> 4;
  const int rng  = w & 3;
  const bool isL2 = (w >= 4);
  const int jo   = rng * 16 + cl;
  const bool jv  = (jo < HH);
  const int bg0  = blockIdx.x * MT;

  for (int i = tid; i < SM_SZ / 4; i += NTH) smf[i] = 0.f;

  // gate-domain scales folded into weights/biases: i,f,o -> -L2E ; g -> +2*L2E
  const float gsc[4] = {-L2E, -L2E, 2.f * L2E, -L2E};

  // ---- B-fragments (weights, bf16 hi/lo, pre-scaled) in registers ----
  // k̂ = kb*32 + gr*8 + s.  L1: kb0-1 = Whh1, plus k=53 carries Wih1 (x slot).
  // L2: kb0-1 = Wih2, kb2-3 = Whh2 (k>=51 pads zero in each range).
  bf8_t Bh[4][4], Bl[4][4];
  #pragma unroll
  for (int g = 0; g < 4; ++g) {
    #pragma unroll
    for (int kb = 0; kb < 4; ++kb) {
      bf8_t vh, vl;
      const bool dead = (!isL2 && kb >= 2);
      const float* Wsrc = isL2 ? (kb < 2 ? Wih2 : Whh2) : Whh1;
      const int kbase = (kb & 1) * 32;
      #pragma unroll
      for (int s = 0; s < 8; ++s) {
        const int ku = kbase + gr * 8 + s;
        float v = (!dead && jv && ku < HH) ? Wsrc[(g * HH + jo) * HH + ku] * gsc[g] : 0.f;
        if (!isL2 && kb == 1 && ku == 53) v = jv ? Wih1[g * HH + jo] * gsc[g] : 0.f;
        const short hh = f2bf(v);
        vh[s] = hh;
        vl[s] = f2bf(v - bf2f(hh));
      }
      Bh[g][kb] = vh; Bl[g][kb] = vl;
    }
  }
  // Wlin B-fragments for the MFMA output projection (used by wave 4 only):
  // col 0 = Wlin hi, col 1 = Wlin lo (unscaled), over k of the h2 ranges.
  bf8_t Bo[2];
  #pragma unroll
  for (int kb = 0; kb < 2; ++kb) {
    bf8_t v;
    #pragma unroll
    for (int s = 0; s < 8; ++s) {
      const int ku = kb * 32 + gr * 8 + s;
      float wv = (ku < HH) ? Wlin[ku] : 0.f;
      const short hh = f2bf(wv);
      v[s] = (cl == 0) ? hh : (cl == 1) ? f2bf(wv - bf2f(hh)) : (short)0;
    }
    Bo[kb] = v;
  }
  float cbv[4], wih1v[4];
  #pragma unroll
  for (int g = 0; g < 4; ++g) {
    cbv[g]   = jv ? (isL2 ? (bih2[g*HH+jo] + bhh2[g*HH+jo])
                          : (bih1[g*HH+jo] + bhh1[g*HH+jo])) * gsc[g] : 0.f;
    wih1v[g] = (jv && !isL2) ? Wih1[g*HH+jo] * gsc[g] : 0.f;
  }
  const float wlv = (jv && isL2) ? Wlin[jo] : 0.f;
  const float bl  = blin[0];
  float cst[4] = {0.f, 0.f, 0.f, 0.f};

  // Scaled-domain LSTM cell with rcp-merged sigmoids:
  //   acc0=-L2E*i, acc1=-L2E*f, acc2=+2L2E*g, acc3=-L2E*o
  //   sigma(i)*tanh(g) = (a2-2)/(a0*a2);  sigma(f)=a3/(a1*a3);  sigma(o)=a1/(a1*a3)
  // 5 exp2 + 3 rcp (was 5+5).  c-tanh keeps graceful 1-2*rcp form (no inf*0).
  auto act_h = [&](const f32x4 acc[4], int r) -> float {
    const float a0 = 1.f + FEXP2(acc[0][r]);
    const float a1 = 1.f + FEXP2(acc[1][r]);
    const float a2 = 1.f + FEXP2(acc[2][r]);
    const float a3 = 1.f + FEXP2(acc[3][r]);
    const float P02 = FRCP(a0 * a2);
    const float P13 = FRCP(a1 * a3);
    const float sitg = (a2 - 2.f) * P02;
    const float sf = a3 * P13;
    const float so = a1 * P13;
    const float cn = sf * cst[r] + sitg;
    cst[r] = cn;
    const float a4 = 1.f + FEXP2(cn * (2.f * L2E));
    return so * (1.f - 2.f * FRCP(a4));
  };

  auto writeOB = [&](int tw, const float ov[4]) {
    if (cl == 0) {
      const int po = (tw >> 4) & 1, cc = tw & 15;
      #pragma unroll
      for (int r = 0; r < 4; ++r)
        smf[OB_O/4 + po*256 + (gr*4 + r)*16 + cc] = ov[r];
    }
  };

  // xv == nullptr -> main phase (x comes in via k=53 of the A fragments)
  auto do_l1 = [&](const int p, const float* xv, const int t) {
    const char* RH = smc + H1H_O + (p ^ 1) * 2048;
    const char* RL = smc + H1L_O + (p ^ 1) * 2048;
    bf8_t a0 = ldA(RH, cl, gr*16), a1 = ldA(RH, cl, 64 + gr*16);
    bf8_t l0 = ldA(RL, cl, gr*16), l1 = ldA(RL, cl, 64 + gr*16);
    f32x4 acc[4];
    __builtin_amdgcn_s_setprio(1);
    #pragma unroll
    for (int g = 0; g < 4; ++g) {
      f32x4 a = {cbv[g], cbv[g], cbv[g], cbv[g]};
      a = MFMA(a0, Bh[g][0], a); a = MFMA(a1, Bh[g][1], a);
      a = MFMA(l0, Bh[g][0], a); a = MFMA(l1, Bh[g][1], a);
      a = MFMA(a0, Bl[g][0], a); a = MFMA(a1, Bl[g][1], a);
      acc[g] = a;
    }
    __builtin_amdgcn_s_setprio(0);
    if (xv) {
      #pragma unroll
      for (int g = 0; g < 4; ++g)
        #pragma unroll
        for (int r = 0; r < 4; ++r) acc[g][r] += wih1v[g] * xv[r];
    }
    char* WH = smc + H1H_O + p * 2048;
    char* WL = smc + H1L_O + p * 2048;
    #pragma unroll
    for (int r = 0; r < 4; ++r) {
      const float hv = act_h(acc, r);
      if (jv) sthl(WH, WL, gr * 4 + r, 2 * jo, hv);
    }
    // wave 3 seeds x(t+1) into k=53 of the buffer being written this step
    if (!xv && rng == 3 && (t + 1) < T_SEQ) {
      if (lane < 16) {
        const float xn = smf[XB_O/4 + (((t+1) >> 4) & 1) * 256 + lane * 16 + ((t+1) & 15)];
        sthl(WH, WL, lane, 2 * 53, xn);
      }
    }
  };

  auto do_l2 = [&](const int q, const bool ar, const int tw) {
    const char* R1H = smc + H1H_O + q * 2048,       *R1L = smc + H1L_O + q * 2048;
    const char* R2H = smc + H2H_O + (q ^ 1) * 2048, *R2L = smc + H2L_O + (q ^ 1) * 2048;
    bf8_t a[4], al[4];
    a[0]  = ldA(R1H, cl, gr*16); a[1]  = ldA(R1H, cl, 64 + gr*16);
    a[2]  = ldA(R2H, cl, gr*16); a[3]  = ldA(R2H, cl, 64 + gr*16);
    al[0] = ldA(R1L, cl, gr*16); al[1] = ldA(R1L, cl, 64 + gr*16);
    al[2] = ldA(R2L, cl, gr*16); al[3] = ldA(R2L, cl, 64 + gr*16);
    f32x4 acc[4];
    f32x4 d = {0.f, 0.f, 0.f, 0.f};
    __builtin_amdgcn_s_setprio(1);
    #pragma unroll
    for (int g = 0; g < 4; ++g) {
      f32x4 ac = {cbv[g], cbv[g], cbv[g], cbv[g]};
      #pragma unroll
      for (int kb = 0; kb < 4; ++kb) ac = MFMA(a[kb],  Bh[g][kb], ac);
      #pragma unroll
      for (int kb = 0; kb < 4; ++kb) ac = MFMA(al[kb], Bh[g][kb], ac);
      #pragma unroll
      for (int kb = 0; kb < 4; ++kb) ac = MFMA(a[kb],  Bl[g][kb], ac);
      acc[g] = ac;
    }
    if (!ar && rng == 0) {           // out(tw) = h2(tw) . Wlin  (4 extra MFMAs, w4)
      d = MFMA(a[3], Bo[1], d); d = MFMA(a[2], Bo[0], d);
      d = MFMA(al[3], Bo[1], d); d = MFMA(al[2], Bo[0], d);
    }
    __builtin_amdgcn_s_setprio(0);
    char* WH = smc + H2H_O + q * 2048;
    char* WL = smc + H2L_O + q * 2048;
    float po[4];
    #pragma unroll
    for (int r = 0; r < 4; ++r) {
      const float hv = act_h(acc, r);
      if (jv) sthl(WH, WL, gr * 4 + r, 2 * jo, hv);
      po[r] = wlv * hv;
    }
    if (!ar) {
      if (rng == 0 && tw >= 0) {
        float ov[4];
        #pragma unroll
        for (int r = 0; r < 4; ++r) ov[r] = d[r] + __shfl_xor(d[r], 1, 64) + bl;
        writeOB(tw, ov);
      }
    } else {
      #pragma unroll
      for (int r = 0; r < 4; ++r) {
        #pragma unroll
        for (int m = 1; m < 16; m <<= 1) po[r] += __shfl_xor(po[r], m, 64);
      }
      if (cl == 0) {
        #pragma unroll
        for (int r = 0; r < 4; ++r)
          smf[PT_O/4 + q*64 + rng*16 + gr*4 + r] = po[r];
      }
    }
  };

  auto finalize = [&](const int q, float ov[4]) {
    #pragma unroll
    for (int r = 0; r < 4; ++r) {
      const int row = gr * 4 + r;
      ov[r] = smf[PT_O/4 + q*64 +  0 + row] + smf[PT_O/4 + q*64 + 16 + row]
            + smf[PT_O/4 + q*64 + 32 + row] + smf[PT_O/4 + q*64 + 48 + row] + bl;
    }
  };
  auto flushOB = [&](int tb) {
    const int q = (tb >> 4) & 1;
    #pragma unroll
    for (int it = 0; it < 4; ++it) {
      const int idx = lane + 64 * it;
      const int r = idx >> 4, tt = idx & 15;
      out[(size_t)(bg0 + r) * T_TOT + tb + tt] = smf[OB_O/4 + q*256 + r*16 + tt];
    }
  };

  __syncthreads();
  if (tid < 256) {
    const int r = tid >> 4, tt = tid & 15;
    smf[XB_O/4 + r*16 + tt] = x[(size_t)(bg0 + r) * T_SEQ + tt];
  }
  if (tid < 16)   // seed x(0) into k=53 of h1 parity-1 (read by do_l1(t=0))
    sthl(smc + H1H_O + 2048, smc + H1L_O + 2048, tid, 2 * 53,
         x[(size_t)(bg0 + tid) * T_SEQ]);
  __syncthreads();

  auto main_step = [&](int t, const int p) {
    if (!isL2) {
      if ((w == 1 || w == 2) && (t & 15) == 0 && (t + 16) < T_SEQ) {
        const int nt = t + 16, par = (nt >> 4) & 1;
        #pragma unroll
        for (int it = 0; it < 2; ++it) {
          const int idx = (w - 1) * 128 + lane + 64 * it;
          const int r = idx >> 4, tt = idx & 15;
          smf[XB_O/4 + par*256 + r*16 + tt] = x[(size_t)(bg0 + r) * T_SEQ + nt + tt];
        }
      }
      if (w == 3 && (t & 15) == 9 && t >= 25) flushOB(((t - 2) & ~15) - 16);
      do_l1(p, nullptr, t);
    } else {
      if (t >= 1) do_l2(p ^ 1, false, t - 2);
    }
  };

  // ======== main pipeline: layer1(t) || layer2(t-1); parity literal ========
  #pragma unroll 1
  for (int t = 0; t < T_SEQ; t += 2) {
    main_step(t, 0);
    __syncthreads();
    main_step(t + 1, 1);
    __syncthreads();
  }
  // ---- drain: layer2(1023) in AR mode (PT for out(1023)); out(1022) via MFMA;
  //      L1 side zeroes the stale k=53 x slots for the AR phase.
  if (isL2) {
    do_l2(1, true, -1);
    if (rng == 0) {                    // out(1022) from h2(1022) (parity 0)
      const char* RH = smc + H2H_O;
      const char* RL = smc + H2L_O;
      bf8_t a2 = ldA(RH, cl, gr*16), a3 = ldA(RH, cl, 64 + gr*16);
      bf8_t b2 = ldA(RL, cl, gr*16), b3 = ldA(RL, cl, 64 + gr*16);
      f32x4 d = {0.f, 0.f, 0.f, 0.f};
      d = MFMA(a3, Bo[1], d); d = MFMA(a2, Bo[0], d);
      d = MFMA(b3, Bo[1], d); d = MFMA(b2, Bo[0], d);
      float ov[4];
      #pragma unroll
      for (int r = 0; r < 4; ++r) ov[r] = d[r] + __shfl_xor(d[r], 1, 64) + bl;
      writeOB(1022, ov);
    }
  } else if (w == 3 && lane < 16) {
    sthl(smc + H1H_O,        smc + H1L_O,        lane, 2 * 53, 0.f);
    sthl(smc + H1H_O + 2048, smc + H1L_O + 2048, lane, 2 * 53, 0.f);
  }
  __syncthreads();

  // ======== autoregressive region: 2 serial phases/step (PT path) ========
  auto ar_step = [&](int t, const int p) {
    if (!isL2) {
      float ov[4];
      finalize(p ^ 1, ov);
      if (w == 0) writeOB(t - 1, ov);
      if (w == 3 && (t & 15) == 8) flushOB(((t - 1) & ~15) - 16);
      do_l1(p, ov, t);
    }
    __syncthreads();
    if (isL2) do_l2(p, true, -1);
    __syncthreads();
  };
  #pragma unroll 1
  for (int t = T_SEQ; t < T_TOT; t += 2) {
    ar_step(t, 0);
    ar_step(t + 1, 1);
  }
  if (!isL2 && w == 0) { float ov[4]; finalize(1, ov); writeOB(T_TOT - 1, ov); }
  __syncthreads();
  if (w == 3) flushOB(T_TOT - 16);
}

extern "C" void kernel_launch(void* const* d_in, const int* in_sizes, int n_in,
                              void* d_out, int out_size, void* d_ws, size_t ws_size,
                              hipStream_t stream) {
  const float* x    = (const float*)d_in[0];
  const float* Wih1 = (const float*)d_in[1];
  const float* Whh1 = (const float*)d_in[2];
  const float* bih1 = (const float*)d_in[3];
  const float* bhh1 = (const float*)d_in[4];
  const float* Wih2 = (const float*)d_in[5];
  const float* Whh2 = (const float*)d_in[6];
  const float* bih2 = (const float*)d_in[7];
  const float* bhh2 = (const float*)d_in[8];
  const float* Wlin = (const float*)d_in[9];
  const float* blin = (const float*)d_in[10];
  float* out = (float*)d_out;

  lstm_mfma_kernel<<<B_TOT / MT, NTH, SM_SZ, stream>>>(
      x, Wih1, Whh1, bih1, bhh1, Wih2, Whh2, bih2, bhh2, Wlin, blin, out);
}

// Round 11
// 1216.661 us; speedup vs baseline: 1.1254x; 1.0687x over previous
//
#include <hip/hip_runtime.h>

#define HH    51
#define T_SEQ 1024
#define T_TOT 1088
#define B_TOT 4096
#define MT    16
#define NTH   512

typedef __attribute__((ext_vector_type(8))) short bf8_t;   // 8 bf16 (4 VGPRs)
typedef __attribute__((ext_vector_type(4))) float f32x4;   // MFMA C/D

// ---- LDS layout (bytes) ----
#define H1H_O 0
#define H1L_O 4096
#define H2H_O 8192
#define H2L_O 12288
#define XB_O  16384   // float [2][16][16]
#define OB_O  18432   // float [2][16][16]
#define PT_O  20480   // float [2][4][16]
#define SM_SZ 20992

#define L2E 1.44269504088896f

#if __has_builtin(__builtin_amdgcn_exp2f)
#define FEXP2 __builtin_amdgcn_exp2f
#else
#define FEXP2 exp2f
#endif
#if __has_builtin(__builtin_amdgcn_rcpf)
#define FRCP __builtin_amdgcn_rcpf
#else
#define FRCP(v) (1.f / (v))
#endif

__device__ __forceinline__ short f2bf(float f) {            // RNE (setup only)
  unsigned u = __builtin_bit_cast(unsigned, f);
  u += 0x7fffu + ((u >> 16) & 1u);
  return (short)(u >> 16);
}
__device__ __forceinline__ float bf2f(short s) {
  unsigned u = ((unsigned)(unsigned short)s) << 16;
  return __builtin_bit_cast(float, u);
}

__device__ __forceinline__ f32x4 MFMA(bf8_t a, bf8_t b, f32x4 c) {
  return __builtin_amdgcn_mfma_f32_16x16x32_bf16(a, b, c, 0, 0, 0);
}
__device__ __forceinline__ bf8_t ldA(const char* base, int row, int off) {
  off ^= ((row & 7) << 4);
  return *reinterpret_cast<const bf8_t*>(base + row * 128 + off);
}
// truncation hi/lo split store: exact residual, err <= 2^-16 rel
__device__ __forceinline__ void sthl(char* WH, char* WL, int row, int boff, float v) {
  const int o = row * 128 + (boff ^ ((row & 7) << 4));
  const unsigned u = __builtin_bit_cast(unsigned, v);
  *reinterpret_cast<short*>(WH + o) = (short)(u >> 16);
  const float rem = v - __builtin_bit_cast(float, u & 0xffff0000u);
  *reinterpret_cast<short*>(WL + o) = (short)(__builtin_bit_cast(unsigned, rem) >> 16);
}

__global__ __launch_bounds__(NTH, 1)
void lstm_mfma_kernel(const float* __restrict__ x,
                      const float* __restrict__ Wih1, const float* __restrict__ Whh1,
                      const float* __restrict__ bih1, const float* __restrict__ bhh1,
                      const float* __restrict__ Wih2, const float* __restrict__ Whh2,
                      const float* __restrict__ bih2, const float* __restrict__ bhh2,
                      const float* __restrict__ Wlin, const float* __restrict__ blin,
                      float* __restrict__ out)
{
  extern __shared__ char smc[];
  float* smf = (float*)smc;
  const int tid  = threadIdx.x;
  const int lane = tid & 63;
  const int w    = tid >> 6;
  const int cl   = lane & 15;
  const int gr   = lane >> 4;
  const int rng  = w & 3;
  const bool isL2 = (w >= 4);
  const int jo   = rng * 16 + cl;
  const bool jv  = (jo < HH);
  const int bg0  = blockIdx.x * MT;

  for (int i = tid; i < SM_SZ / 4; i += NTH) smf[i] = 0.f;

  // gate-domain scales folded into weights/biases: i,f,o -> -L2E ; g -> +2*L2E
  const float gsc[4] = {-L2E, -L2E, 2.f * L2E, -L2E};

  // ---- B-fragments (weights, bf16 hi/lo, pre-scaled) in registers ----
  // k̂ = kb*32 + gr*8 + s.  L1: kb0-1 = Whh1, plus k=53 carries Wih1 (x slot).
  // L2: kb0-1 = Wih2, kb2-3 = Whh2 (k>=51 pads zero in each range).
  bf8_t Bh[4][4], Bl[4][4];
  #pragma unroll
  for (int g = 0; g < 4; ++g) {
    #pragma unroll
    for (int kb = 0; kb < 4; ++kb) {
      bf8_t vh, vl;
      const bool dead = (!isL2 && kb >= 2);
      const float* Wsrc = isL2 ? (kb < 2 ? Wih2 : Whh2) : Whh1;
      const int kbase = (kb & 1) * 32;
      #pragma unroll
      for (int s = 0; s < 8; ++s) {
        const int ku = kbase + gr * 8 + s;
        float v = (!dead && jv && ku < HH) ? Wsrc[(g * HH + jo) * HH + ku] * gsc[g] : 0.f;
        if (!isL2 && kb == 1 && ku == 53) v = jv ? Wih1[g * HH + jo] * gsc[g] : 0.f;
        const short hh = f2bf(v);
        vh[s] = hh;
        vl[s] = f2bf(v - bf2f(hh));
      }
      Bh[g][kb] = vh; Bl[g][kb] = vl;
    }
  }
  // Wlin B-fragments for the MFMA output projection (used by wave 0 / drain):
  // col 0 = Wlin hi, col 1 = Wlin lo (unscaled), over k of the h2 ranges.
  bf8_t Bo[2];
  #pragma unroll
  for (int kb = 0; kb < 2; ++kb) {
    bf8_t v;
    #pragma unroll
    for (int s = 0; s < 8; ++s) {
      const int ku = kb * 32 + gr * 8 + s;
      float wv = (ku < HH) ? Wlin[ku] : 0.f;
      const short hh = f2bf(wv);
      v[s] = (cl == 0) ? hh : (cl == 1) ? f2bf(wv - bf2f(hh)) : (short)0;
    }
    Bo[kb] = v;
  }
  float cbv[4], wih1v[4];
  #pragma unroll
  for (int g = 0; g < 4; ++g) {
    cbv[g]   = jv ? (isL2 ? (bih2[g*HH+jo] + bhh2[g*HH+jo])
                          : (bih1[g*HH+jo] + bhh1[g*HH+jo])) * gsc[g] : 0.f;
    wih1v[g] = (jv && !isL2) ? Wih1[g*HH+jo] * gsc[g] : 0.f;
  }
  const float wlv = (jv && isL2) ? Wlin[jo] : 0.f;
  const float bl  = blin[0];
  float cst[4] = {0.f, 0.f, 0.f, 0.f};

  // Scaled-domain LSTM cell with rcp-merged sigmoids (5 exp2 + 3 rcp)
  auto act_h = [&](const f32x4 acc[4], int r) -> float {
    const float a0 = 1.f + FEXP2(acc[0][r]);
    const float a1 = 1.f + FEXP2(acc[1][r]);
    const float a2 = 1.f + FEXP2(acc[2][r]);
    const float a3 = 1.f + FEXP2(acc[3][r]);
    const float P02 = FRCP(a0 * a2);
    const float P13 = FRCP(a1 * a3);
    const float sitg = (a2 - 2.f) * P02;
    const float sf = a3 * P13;
    const float so = a1 * P13;
    const float cn = sf * cst[r] + sitg;
    cst[r] = cn;
    const float a4 = 1.f + FEXP2(cn * (2.f * L2E));
    return so * (1.f - 2.f * FRCP(a4));
  };

  auto writeOB = [&](int tw, const float ov[4]) {
    if (cl == 0) {
      const int po = (tw >> 4) & 1, cc = tw & 15;
      #pragma unroll
      for (int r = 0; r < 4; ++r)
        smf[OB_O/4 + po*256 + (gr*4 + r)*16 + cc] = ov[r];
    }
  };

  // xv == nullptr -> main phase (x comes in via k=53 of the A fragments)
  auto do_l1 = [&](const int p, const float* xv, const int t) {
    const char* RH = smc + H1H_O + (p ^ 1) * 2048;
    const char* RL = smc + H1L_O + (p ^ 1) * 2048;
    bf8_t a0 = ldA(RH, cl, gr*16), a1 = ldA(RH, cl, 64 + gr*16);
    bf8_t l0 = ldA(RL, cl, gr*16), l1 = ldA(RL, cl, 64 + gr*16);
    f32x4 acc[4];
    #pragma unroll
    for (int g = 0; g < 4; ++g) {
      f32x4 a = {cbv[g], cbv[g], cbv[g], cbv[g]};
      a = MFMA(a0, Bh[g][0], a); a = MFMA(a1, Bh[g][1], a);
      a = MFMA(l0, Bh[g][0], a); a = MFMA(l1, Bh[g][1], a);
      a = MFMA(a0, Bl[g][0], a); a = MFMA(a1, Bl[g][1], a);
      acc[g] = a;
    }
    if (xv) {
      #pragma unroll
      for (int g = 0; g < 4; ++g)
        #pragma unroll
        for (int r = 0; r < 4; ++r) acc[g][r] += wih1v[g] * xv[r];
    }
    char* WH = smc + H1H_O + p * 2048;
    char* WL = smc + H1L_O + p * 2048;
    #pragma unroll
    for (int r = 0; r < 4; ++r) {
      const float hv = act_h(acc, r);
      if (jv) sthl(WH, WL, gr * 4 + r, 2 * jo, hv);
    }
    // wave 3 seeds x(t+1) into k=53 of the buffer being written this step
    if (!xv && rng == 3 && (t + 1) < T_SEQ) {
      if (lane < 16) {
        const float xn = smf[XB_O/4 + (((t+1) >> 4) & 1) * 256 + lane * 16 + ((t+1) & 15)];
        sthl(WH, WL, lane, 2 * 53, xn);
      }
    }
  };

  // Split-load L2: h1 frags -> 24 MFMA -> (sched fence) h2 frags -> 24 MFMA.
  auto do_l2 = [&](const int q, const bool ar) {
    const char* R1H = smc + H1H_O + q * 2048, *R1L = smc + H1L_O + q * 2048;
    bf8_t a0 = ldA(R1H, cl, gr*16), a1 = ldA(R1H, cl, 64 + gr*16);
    bf8_t u0 = ldA(R1L, cl, gr*16), u1 = ldA(R1L, cl, 64 + gr*16);
    f32x4 acc[4];
    #pragma unroll
    for (int g = 0; g < 4; ++g) {
      f32x4 ac = {cbv[g], cbv[g], cbv[g], cbv[g]};
      ac = MFMA(a0, Bh[g][0], ac); ac = MFMA(a1, Bh[g][1], ac);
      ac = MFMA(u0, Bh[g][0], ac); ac = MFMA(u1, Bh[g][1], ac);
      ac = MFMA(a0, Bl[g][0], ac); ac = MFMA(a1, Bl[g][1], ac);
      acc[g] = ac;
    }
    __builtin_amdgcn_sched_barrier(0);   // keep h2 loads below the h1-side MFMAs
    const char* R2H = smc + H2H_O + (q ^ 1) * 2048, *R2L = smc + H2L_O + (q ^ 1) * 2048;
    bf8_t b0 = ldA(R2H, cl, gr*16), b1 = ldA(R2H, cl, 64 + gr*16);
    bf8_t v0 = ldA(R2L, cl, gr*16), v1 = ldA(R2L, cl, 64 + gr*16);
    #pragma unroll
    for (int g = 0; g < 4; ++g) {
      f32x4 ac = acc[g];
      ac = MFMA(b0, Bh[g][2], ac); ac = MFMA(b1, Bh[g][3], ac);
      ac = MFMA(v0, Bh[g][2], ac); ac = MFMA(v1, Bh[g][3], ac);
      ac = MFMA(b0, Bl[g][2], ac); ac = MFMA(b1, Bl[g][3], ac);
      acc[g] = ac;
    }
    char* WH = smc + H2H_O + q * 2048;
    char* WL = smc + H2L_O + q * 2048;
    float po[4];
    #pragma unroll
    for (int r = 0; r < 4; ++r) {
      const float hv = act_h(acc, r);
      if (jv) sthl(WH, WL, gr * 4 + r, 2 * jo, hv);
      po[r] = wlv * hv;
    }
    if (ar) {
      #pragma unroll
      for (int r = 0; r < 4; ++r) {
        #pragma unroll
        for (int m = 1; m < 16; m <<= 1) po[r] += __shfl_xor(po[r], m, 64);
      }
      if (cl == 0) {
        #pragma unroll
        for (int r = 0; r < 4; ++r)
          smf[PT_O/4 + q*64 + rng*16 + gr*4 + r] = po[r];
      }
    }
  };

  auto finalize = [&](const int q, float ov[4]) {
    #pragma unroll
    for (int r = 0; r < 4; ++r) {
      const int row = gr * 4 + r;
      ov[r] = smf[PT_O/4 + q*64 +  0 + row] + smf[PT_O/4 + q*64 + 16 + row]
            + smf[PT_O/4 + q*64 + 32 + row] + smf[PT_O/4 + q*64 + 48 + row] + bl;
    }
  };
  auto flushOB = [&](int tb) {
    const int q = (tb >> 4) & 1;
    #pragma unroll
    for (int it = 0; it < 4; ++it) {
      const int idx = lane + 64 * it;
      const int r = idx >> 4, tt = idx & 15;
      out[(size_t)(bg0 + r) * T_TOT + tb + tt] = smf[OB_O/4 + q*256 + r*16 + tt];
    }
  };

  __syncthreads();
  if (tid < 256) {
    const int r = tid >> 4, tt = tid & 15;
    smf[XB_O/4 + r*16 + tt] = x[(size_t)(bg0 + r) * T_SEQ + tt];
  }
  if (tid < 16)   // seed x(0) into k=53 of h1 parity-1 (read by do_l1(t=0))
    sthl(smc + H1H_O + 2048, smc + H1L_O + 2048, tid, 2 * 53,
         x[(size_t)(bg0 + tid) * T_SEQ]);
  __syncthreads();

  // L2 waves are the per-step critical path: persistent priority boost.
  if (isL2) __builtin_amdgcn_s_setprio(1);

  auto main_step = [&](int t, const int p) {
    if (!isL2) {
      if ((w == 1 || w == 2) && (t & 15) == 0 && (t + 16) < T_SEQ) {
        const int nt = t + 16, par = (nt >> 4) & 1;
        #pragma unroll
        for (int it = 0; it < 2; ++it) {
          const int idx = (w - 1) * 128 + lane + 64 * it;
          const int r = idx >> 4, tt = idx & 15;
          smf[XB_O/4 + par*256 + r*16 + tt] = x[(size_t)(bg0 + r) * T_SEQ + nt + tt];
        }
      }
      if (w == 3 && (t & 15) == 9 && t >= 25) flushOB(((t - 2) & ~15) - 16);
      do_l1(p, nullptr, t);
      if (w == 0 && t >= 2) {   // out(t-2) = h2(t-2)·Wlin ; h2(t-2) lives in buf p
        const char* PH = smc + H2H_O + p * 2048;
        const char* PL = smc + H2L_O + p * 2048;
        bf8_t b0 = ldA(PH, cl, gr*16), b1 = ldA(PH, cl, 64 + gr*16);
        bf8_t v0 = ldA(PL, cl, gr*16), v1 = ldA(PL, cl, 64 + gr*16);
        f32x4 d = {0.f, 0.f, 0.f, 0.f};
        d = MFMA(b1, Bo[1], d); d = MFMA(b0, Bo[0], d);
        d = MFMA(v1, Bo[1], d); d = MFMA(v0, Bo[0], d);
        float ov[4];
        #pragma unroll
        for (int r = 0; r < 4; ++r) ov[r] = d[r] + __shfl_xor(d[r], 1, 64) + bl;
        writeOB(t - 2, ov);
      }
    } else {
      if (t >= 1) do_l2(p ^ 1, false);
    }
  };

  // ======== main pipeline: layer1(t) || layer2(t-1); parity literal ========
  #pragma unroll 1
  for (int t = 0; t < T_SEQ; t += 2) {
    main_step(t, 0);
    __syncthreads();
    main_step(t + 1, 1);
    __syncthreads();
  }
  // ---- drain: layer2(1023) in AR mode (PT for out(1023)); out(1022) via MFMA;
  //      L1 side zeroes the stale k=53 x slots for the AR phase.
  if (isL2) {
    do_l2(1, true);
    if (rng == 0) {                    // out(1022) from h2(1022) (parity 0)
      const char* RH = smc + H2H_O;
      const char* RL = smc + H2L_O;
      bf8_t a2 = ldA(RH, cl, gr*16), a3 = ldA(RH, cl, 64 + gr*16);
      bf8_t b2 = ldA(RL, cl, gr*16), b3 = ldA(RL, cl, 64 + gr*16);
      f32x4 d = {0.f, 0.f, 0.f, 0.f};
      d = MFMA(a3, Bo[1], d); d = MFMA(a2, Bo[0], d);
      d = MFMA(b3, Bo[1], d); d = MFMA(b2, Bo[0], d);
      float ov[4];
      #pragma unroll
      for (int r = 0; r < 4; ++r) ov[r] = d[r] + __shfl_xor(d[r], 1, 64) + bl;
      writeOB(1022, ov);
    }
  } else if (w == 3 && lane < 16) {
    sthl(smc + H1H_O,        smc + H1L_O,        lane, 2 * 53, 0.f);
    sthl(smc + H1H_O + 2048, smc + H1L_O + 2048, lane, 2 * 53, 0.f);
  }
  __syncthreads();

  // ======== autoregressive region: 2 serial phases/step (PT path) ========
  auto ar_step = [&](int t, const int p) {
    if (!isL2) {
      float ov[4];
      finalize(p ^ 1, ov);
      if (w == 0) writeOB(t - 1, ov);
      if (w == 3 && (t & 15) == 8) flushOB(((t - 1) & ~15) - 16);
      do_l1(p, ov, t);
    }
    __syncthreads();
    if (isL2) do_l2(p, true);
    __syncthreads();
  };
  #pragma unroll 1
  for (int t = T_SEQ; t < T_TOT; t += 2) {
    ar_step(t, 0);
    ar_step(t + 1, 1);
  }
  if (!isL2 && w == 0) { float ov[4]; finalize(1, ov); writeOB(T_TOT - 1, ov); }
  __syncthreads();
  if (w == 3) flushOB(T_TOT - 16);
}

extern "C" void kernel_launch(void* const* d_in, const int* in_sizes, int n_in,
                              void* d_out, int out_size, void* d_ws, size_t ws_size,
                              hipStream_t stream) {
  const float* x    = (const float*)d_in[0];
  const float* Wih1 = (const float*)d_in[1];
  const float* Whh1 = (const float*)d_in[2];
  const float* bih1 = (const float*)d_in[3];
  const float* bhh1 = (const float*)d_in[4];
  const float* Wih2 = (const float*)d_in[5];
  const float* Whh2 = (const float*)d_in[6];
  const float* bih2 = (const float*)d_in[7];
  const float* bhh2 = (const float*)d_in[8];
  const float* Wlin = (const float*)d_in[9];
  const float* blin = (const float*)d_in[10];
  float* out = (float*)d_out;

  lstm_mfma_kernel<<<B_TOT / MT, NTH, SM_SZ, stream>>>(
      x, Wih1, Whh1, bih1, bhh1, Wih2, Whh2, bih2, bhh2, Wlin, blin, out);
}